// Round 3
// baseline (2705.576 us; speedup 1.0000x reference)
//
#include <hip/hip_runtime.h>
#include <hip/hip_bf16.h>

// LayoutLMv3 encoder forward, bf16-MFMA implementation.
// L=12 D=768 H=12 DH=64 FF=3072 B=4 S=512.

typedef __attribute__((ext_vector_type(8))) short short8;
typedef __attribute__((ext_vector_type(4))) float f32x4;
typedef __attribute__((ext_vector_type(4))) unsigned int u32x4;
typedef __attribute__((ext_vector_type(4))) unsigned short us4;

#define DEVI static __device__ __forceinline__

DEVI unsigned short f2bf(float f) {          // RNE f32 -> bf16
  union { float f; unsigned u; } x; x.f = f;
  unsigned u = x.u;
  u += 0x7fffu + ((u >> 16) & 1u);
  return (unsigned short)(u >> 16);
}
DEVI float bf2f(unsigned short h) {
  union { unsigned u; float f; } x; x.u = ((unsigned)h) << 16;
  return x.f;
}
// bijective XCD-contiguous block swizzle (m204 form)
DEVI int xcd_swz(int bid, int nwg) {
  int q = nwg >> 3, r = nwg & 7;
  int x = bid & 7, o = bid >> 3;
  return (x < r ? x * (q + 1) : r * (q + 1) + (x - r) * q) + o;
}

// ---- 64x64 GEMM tile core: C = A(bf16,global) @ W(f32,global), acc f32 ----
// 4 waves, wave w owns rows [16w,16w+16). BK=64. W staged to LDS as B^T bf16
// with XOR swizzle addr = n*128 + (2k ^ ((n&7)<<4)) -> bank-uniform b128 r/w.
DEVI void gemm64(const unsigned short* __restrict__ A, int lda,
                 const float* __restrict__ W, int ldw, int K,
                 int m0, f32x4 acc[4], char* lds) {
  const int tid = threadIdx.x;
  const int l = tid & 63, w = tid >> 6;
  const int n_st = tid & 63;            // staging: column owned by this thread
  const int kb = (tid >> 6) << 4;       // staging: k-base 0/16/32/48
  const unsigned short* Ar = A + (size_t)(m0 + 16 * w + (l & 15)) * lda + ((l >> 4) << 3);
  for (int kt = 0; kt < K; kt += 64) {
    float f[16];
#pragma unroll
    for (int j = 0; j < 16; ++j)
      f[j] = W[(size_t)(kt + kb + j) * ldw + n_st];   // coalesced across lanes
    __syncthreads();                                  // prev iter done reading LDS
#pragma unroll
    for (int c = 0; c < 2; ++c) {
      u32x4 p;
#pragma unroll
      for (int q2 = 0; q2 < 4; ++q2)
        p[q2] = (unsigned)f2bf(f[c * 8 + q2 * 2]) | ((unsigned)f2bf(f[c * 8 + q2 * 2 + 1]) << 16);
      int koff = (kb + c * 8) << 1;                   // 16B-aligned
      int addr = (n_st << 7) + (koff ^ ((n_st & 7) << 4));
      *(u32x4*)(lds + addr) = p;
    }
    __syncthreads();
#pragma unroll
    for (int ks = 0; ks < 2; ++ks) {
      short8 a = *(const short8*)(Ar + kt + ks * 32);
#pragma unroll
      for (int fb = 0; fb < 4; ++fb) {
        int nn = (fb << 4) + (l & 15);
        int koff = (ks * 32 + ((l >> 4) << 3)) << 1;
        int addr = (nn << 7) + (koff ^ ((nn & 7) << 4));
        short8 b = *(const short8*)(lds + addr);
        acc[fb] = __builtin_amdgcn_mfma_f32_16x16x32_bf16(a, b, acc[fb], 0, 0, 0);
      }
    }
  }
}

// ---- fused QKV GEMM: n-tiles 0..11 -> Q (scaled 1/8), 12..23 -> K, 24..35 -> V^T
__global__ __launch_bounds__(256) void k_qkv(
    const unsigned short* __restrict__ xb,
    const float* __restrict__ Wq, const float* __restrict__ Wk, const float* __restrict__ Wv,
    const float* __restrict__ bq, const float* __restrict__ bk, const float* __restrict__ bv,
    unsigned short* __restrict__ q_out, unsigned short* __restrict__ k_out,
    unsigned short* __restrict__ vT_out, int layer) {
  __shared__ u32x4 lds4[512];
  char* lds = (char*)lds4;
  const int wid = xcd_swz(blockIdx.x, gridDim.x);
  const int bm = wid % 32, bn = wid / 32;
  const int which = bn / 12;
  const int nloc = (bn % 12) * 64;
  const float* W = (which == 0 ? Wq : which == 1 ? Wk : Wv) + (size_t)layer * 589824 + nloc;
  const float* bias = (which == 0 ? bq : which == 1 ? bk : bv) + layer * 768 + nloc;
  f32x4 acc[4];
#pragma unroll
  for (int i = 0; i < 4; ++i) acc[i] = (f32x4){0.f, 0.f, 0.f, 0.f};
  gemm64(xb, 768, W, 768, 768, bm * 64, acc, lds);
  const int tid = threadIdx.x, l = tid & 63, w = tid >> 6;
  const int h = nloc >> 6;
  const int r0 = bm * 64 + 16 * w + ((l >> 4) << 2);
  const int batch = r0 >> 9, s0 = r0 & 511;
  const int bh = batch * 12 + h;
  const float scale = (which == 0) ? 0.125f : 1.0f;   // 1/sqrt(DH)=1/8 folded into Q
#pragma unroll
  for (int fb = 0; fb < 4; ++fb) {
    const int c = (fb << 4) + (l & 15);
    const float bv_ = bias[c];
    if (which == 2) {
      us4 pk;
#pragma unroll
      for (int j = 0; j < 4; ++j) pk[j] = f2bf(acc[fb][j] + bv_);
      *(us4*)(vT_out + ((size_t)bh * 64 + c) * 512 + s0) = pk;   // V transposed [bh][dh][s]
    } else {
      unsigned short* dst = (which == 0 ? q_out : k_out);
#pragma unroll
      for (int j = 0; j < 4; ++j)
        dst[((size_t)bh * 512 + s0 + j) * 64 + c] = f2bf((acc[fb][j] + bv_) * scale);
    }
  }
}

// ---- fused scores + bias + softmax -> probs (bf16). Block: 64 q-rows x full 512.
__global__ __launch_bounds__(256) void k_attn(
    const unsigned short* __restrict__ qb, const unsigned short* __restrict__ kb,
    const unsigned short* __restrict__ biasb, unsigned short* __restrict__ probs) {
  const int bh = blockIdx.y;
  const int q0 = blockIdx.x * 64;
  const int tid = threadIdx.x, l = tid & 63, w = tid >> 6;
  const unsigned short* Q = qb + ((size_t)bh * 512 + q0 + 16 * w + (l & 15)) * 64 + ((l >> 4) << 3);
  const unsigned short* Kp = kb + (size_t)bh * 32768 + (size_t)(l & 15) * 64 + ((l >> 4) << 3);
  f32x4 acc[32];
#pragma unroll
  for (int i = 0; i < 32; ++i) acc[i] = (f32x4){0.f, 0.f, 0.f, 0.f};
#pragma unroll
  for (int ks = 0; ks < 2; ++ks) {
    short8 a = *(const short8*)(Q + ks * 32);
#pragma unroll
    for (int f = 0; f < 32; ++f) {
      short8 b = *(const short8*)(Kp + (size_t)f * 1024 + ks * 32);
      acc[f] = __builtin_amdgcn_mfma_f32_16x16x32_bf16(a, b, acc[f], 0, 0, 0);
    }
  }
  const int r0 = q0 + 16 * w + ((l >> 4) << 2);
  const unsigned short* Brow = biasb + ((size_t)bh * 512 + r0) * 512 + (l & 15);
  unsigned short* Prow = probs + ((size_t)bh * 512 + r0) * 512 + (l & 15);
#pragma unroll
  for (int j = 0; j < 4; ++j) {
    float m = -3.0e38f;
#pragma unroll
    for (int f = 0; f < 32; ++f) {
      float v = acc[f][j] + bf2f(Brow[(size_t)j * 512 + (f << 4)]);
      acc[f][j] = v;
      m = fmaxf(m, v);
    }
#pragma unroll
    for (int off = 1; off < 16; off <<= 1) m = fmaxf(m, __shfl_xor(m, off));
    float s = 0.f;
#pragma unroll
    for (int f = 0; f < 32; ++f) {
      float e = __expf(acc[f][j] - m);
      acc[f][j] = e;
      s += e;
    }
#pragma unroll
    for (int off = 1; off < 16; off <<= 1) s += __shfl_xor(s, off);
    const float inv = 1.0f / s;
#pragma unroll
    for (int f = 0; f < 32; ++f)
      Prow[(size_t)j * 512 + (f << 4)] = f2bf(acc[f][j] * inv);
  }
}

// ---- PV: ctx[b,s,h*64+dh] = probs @ V  (V read from transposed vT, no LDS)
__global__ __launch_bounds__(256) void k_pv(
    const unsigned short* __restrict__ probs, const unsigned short* __restrict__ vT,
    unsigned short* __restrict__ ctx) {
  const int bh = blockIdx.y;
  const int q0 = blockIdx.x * 64;
  const int tid = threadIdx.x, l = tid & 63, w = tid >> 6;
  const unsigned short* Ar = probs + ((size_t)bh * 512 + q0 + 16 * w + (l & 15)) * 512 + ((l >> 4) << 3);
  const unsigned short* Vb = vT + (size_t)bh * 32768 + (size_t)(l & 15) * 512 + ((l >> 4) << 3);
  f32x4 acc[4];
#pragma unroll
  for (int i = 0; i < 4; ++i) acc[i] = (f32x4){0.f, 0.f, 0.f, 0.f};
#pragma unroll 4
  for (int kt = 0; kt < 512; kt += 32) {
    short8 a = *(const short8*)(Ar + kt);
#pragma unroll
    for (int f = 0; f < 4; ++f) {
      short8 b = *(const short8*)(Vb + (size_t)f * 8192 + kt);
      acc[f] = __builtin_amdgcn_mfma_f32_16x16x32_bf16(a, b, acc[f], 0, 0, 0);
    }
  }
  const int batch = bh / 12, h = bh % 12;
  const int r0 = q0 + 16 * w + ((l >> 4) << 2);
#pragma unroll
  for (int fb = 0; fb < 4; ++fb) {
    const int c = (fb << 4) + (l & 15);
#pragma unroll
    for (int j = 0; j < 4; ++j)
      ctx[((size_t)(batch * 512 + r0 + j)) * 768 + h * 64 + c] = f2bf(acc[fb][j]);
  }
}

// ---- generic GEMM + bias -> f32 out
__global__ __launch_bounds__(256) void k_gemm_bias(
    const unsigned short* __restrict__ A, int lda, int K,
    const float* __restrict__ W, int ldw,
    const float* __restrict__ bias, float* __restrict__ outf, int N, int nbm) {
  __shared__ u32x4 lds4[512];
  char* lds = (char*)lds4;
  const int wid = xcd_swz(blockIdx.x, gridDim.x);
  const int bm = wid % nbm, bn = wid / nbm;
  f32x4 acc[4];
#pragma unroll
  for (int i = 0; i < 4; ++i) acc[i] = (f32x4){0.f, 0.f, 0.f, 0.f};
  gemm64(A, lda, W + bn * 64, ldw, K, bm * 64, acc, lds);
  const int tid = threadIdx.x, l = tid & 63, w = tid >> 6;
  const int r0 = bm * 64 + 16 * w + ((l >> 4) << 2);
  const int c0 = bn * 64;
#pragma unroll
  for (int fb = 0; fb < 4; ++fb) {
    const int c = c0 + (fb << 4) + (l & 15);
    const float bb = bias[c];
#pragma unroll
    for (int j = 0; j < 4; ++j)
      outf[(size_t)(r0 + j) * N + c] = acc[fb][j] + bb;
  }
}

// ---- GEMM + bias + exact GELU -> bf16 out
__global__ __launch_bounds__(256) void k_gemm_gelu(
    const unsigned short* __restrict__ A, int lda, int K,
    const float* __restrict__ W, int ldw,
    const float* __restrict__ bias, unsigned short* __restrict__ outb, int N, int nbm) {
  __shared__ u32x4 lds4[512];
  char* lds = (char*)lds4;
  const int wid = xcd_swz(blockIdx.x, gridDim.x);
  const int bm = wid % nbm, bn = wid / nbm;
  f32x4 acc[4];
#pragma unroll
  for (int i = 0; i < 4; ++i) acc[i] = (f32x4){0.f, 0.f, 0.f, 0.f};
  gemm64(A, lda, W + bn * 64, ldw, K, bm * 64, acc, lds);
  const int tid = threadIdx.x, l = tid & 63, w = tid >> 6;
  const int r0 = bm * 64 + 16 * w + ((l >> 4) << 2);
  const int c0 = bn * 64;
#pragma unroll
  for (int fb = 0; fb < 4; ++fb) {
    const int c = c0 + (fb << 4) + (l & 15);
    const float bb = bias[c];
#pragma unroll
    for (int j = 0; j < 4; ++j) {
      float v = acc[fb][j] + bb;
      v = 0.5f * v * (1.0f + erff(v * 0.70710678118654752f));
      outb[(size_t)(r0 + j) * N + c] = f2bf(v);
    }
  }
}

// ---- residual + LayerNorm, writes f32 + bf16 copies
__global__ __launch_bounds__(256) void k_ln(
    const float* __restrict__ x, const float* __restrict__ res,
    const float* __restrict__ g, const float* __restrict__ bb,
    float* __restrict__ outf, unsigned short* __restrict__ outb) {
  const int row = blockIdx.x, tid = threadIdx.x;
  const float* X = x + (size_t)row * 768;
  const float* R = res + (size_t)row * 768;
  float v[3];
  float s = 0.f;
#pragma unroll
  for (int i = 0; i < 3; ++i) { v[i] = X[tid + (i << 8)] + R[tid + (i << 8)]; s += v[i]; }
  __shared__ float red[4];
#pragma unroll
  for (int off = 32; off; off >>= 1) s += __shfl_xor(s, off);
  if ((tid & 63) == 0) red[tid >> 6] = s;
  __syncthreads();
  const float mu = (red[0] + red[1] + red[2] + red[3]) * (1.f / 768.f);
  float s2 = 0.f;
#pragma unroll
  for (int i = 0; i < 3; ++i) { float d = v[i] - mu; s2 += d * d; }
  __syncthreads();
#pragma unroll
  for (int off = 32; off; off >>= 1) s2 += __shfl_xor(s2, off);
  if ((tid & 63) == 0) red[tid >> 6] = s2;
  __syncthreads();
  const float rstd = rsqrtf((red[0] + red[1] + red[2] + red[3]) * (1.f / 768.f) + 1e-5f);
#pragma unroll
  for (int i = 0; i < 3; ++i) {
    const int c = tid + (i << 8);
    const float o = (v[i] - mu) * rstd * g[c] + bb[c];
    outf[(size_t)row * 768 + c] = o;
    outb[(size_t)row * 768 + c] = f2bf(o);
  }
}

__global__ __launch_bounds__(256) void k_init(const float* __restrict__ h,
                                              float* __restrict__ xf,
                                              unsigned short* __restrict__ xb, int n) {
  int i = blockIdx.x * 256 + threadIdx.x;
  if (i < n) { float v = h[i]; xf[i] = v; xb[i] = f2bf(v); }
}

// ---- relative-position bucket helper (exact int semantics of reference)
DEVI int rbucket(int rp, int nb, int mex) {
  int ret = rp > 0 ? nb : 0;
  int n = rp < 0 ? -rp : rp;
  if (n < mex) return ret + n;
  // ratio max_distance/max_exact == 16 for both tables; 1/ln(16):
  float v = logf((float)n / (float)mex) * 0.36067376022224085f * (float)(nb - mex);
  int vi = mex + (int)v;                 // truncation matches astype(int32)
  vi = vi < (nb - 1) ? vi : (nb - 1);
  return ret + vi;
}

// ---- bias precompute: bias[b,h,i,j] = (rel_w[b1]+relx[bx]+rely[by])/8 + mask[b,j]
__global__ __launch_bounds__(256) void k_bias(
    const int* __restrict__ pos, const int* __restrict__ bbox,
    const float* __restrict__ mask,
    const float* __restrict__ rel_w, const float* __restrict__ relx_w,
    const float* __restrict__ rely_w, unsigned short* __restrict__ biasb) {
  __shared__ float tw[1920];
  for (int i = threadIdx.x; i < 1920; i += 256)
    tw[i] = i < 384 ? rel_w[i] : (i < 1152 ? relx_w[i - 384] : rely_w[i - 1152]);
  __syncthreads();
  const int blk = blockIdx.x;
  const int b = blk >> 9, qi = blk & 511;
  const int pi = pos[(b << 9) + qi];
  const int pxi = bbox[(((b << 9) + qi) << 2) + 0];
  const int pyi = bbox[(((b << 9) + qi) << 2) + 3];
  for (int j = threadIdx.x; j < 512; j += 256) {
    const int idx = (b << 9) + j;
    const int b1 = rbucket(pos[idx] - pi, 16, 8);
    const int bx = rbucket(bbox[(idx << 2) + 0] - pxi, 32, 16);
    const int by = rbucket(bbox[(idx << 2) + 3] - pyi, 32, 16);
    const float mk = mask[idx];
    const float* r1 = tw + b1 * 12;
    const float* r2 = tw + 384 + bx * 12;
    const float* r3 = tw + 1152 + by * 12;
#pragma unroll
    for (int h = 0; h < 12; ++h) {
      float v = (r1[h] + r2[h] + r3[h]) * 0.125f + mk;
      biasb[(((size_t)(b * 12 + h) * 512) + qi) * 512 + j] = f2bf(v);
    }
  }
}

extern "C" void kernel_launch(void* const* d_in, const int* in_sizes, int n_in,
                              void* d_out, int out_size, void* d_ws, size_t ws_size,
                              hipStream_t stream) {
  const float* hid  = (const float*)d_in[0];
  const float* mask = (const float*)d_in[1];
  const int*   pos  = (const int*)d_in[2];
  const int*   bbx  = (const int*)d_in[3];
  const float* Wq = (const float*)d_in[4];  const float* bq = (const float*)d_in[5];
  const float* Wk = (const float*)d_in[6];  const float* bk = (const float*)d_in[7];
  const float* Wv = (const float*)d_in[8];  const float* bv = (const float*)d_in[9];
  const float* Wo = (const float*)d_in[10]; const float* bo = (const float*)d_in[11];
  const float* g1 = (const float*)d_in[12]; const float* be1 = (const float*)d_in[13];
  const float* Wi = (const float*)d_in[14]; const float* bi = (const float*)d_in[15];
  const float* W2 = (const float*)d_in[16]; const float* b2 = (const float*)d_in[17];
  const float* g2 = (const float*)d_in[18]; const float* be2 = (const float*)d_in[19];
  const float* relw  = (const float*)d_in[20];
  const float* relxw = (const float*)d_in[21];
  const float* relyw = (const float*)d_in[22];

  char* ws = (char*)d_ws;
  size_t off = 0;
  auto alloc = [&](size_t b) -> char* {
    char* p = ws + off; off += (b + 255) & ~(size_t)255; return p;
  };
  unsigned short* biasb = (unsigned short*)alloc(25165824); // [48][512][512] bf16
  unsigned short* probs = (unsigned short*)alloc(25165824);
  float* xf  = (float*)alloc(6291456);
  float* tmp = (float*)alloc(6291456);
  float* aof = (float*)alloc(6291456);
  unsigned short* xb  = (unsigned short*)alloc(3145728);
  unsigned short* qb  = (unsigned short*)alloc(3145728);
  unsigned short* kb  = (unsigned short*)alloc(3145728);
  unsigned short* vT  = (unsigned short*)alloc(3145728);
  unsigned short* ctx = (unsigned short*)alloc(3145728);
  unsigned short* aob = (unsigned short*)alloc(3145728);
  unsigned short* hb  = (unsigned short*)alloc(12582912);  // [2048][3072] bf16

  k_bias<<<2048, 256, 0, stream>>>(pos, bbx, mask, relw, relxw, relyw, biasb);
  k_init<<<6144, 256, 0, stream>>>(hid, xf, xb, 2048 * 768);

  for (int lyr = 0; lyr < 12; ++lyr) {
    k_qkv<<<1152, 256, 0, stream>>>(xb, Wq, Wk, Wv, bq, bk, bv, qb, kb, vT, lyr);
    k_attn<<<dim3(8, 48), 256, 0, stream>>>(qb, kb, biasb, probs);
    k_pv<<<dim3(8, 48), 256, 0, stream>>>(probs, vT, ctx);
    k_gemm_bias<<<384, 256, 0, stream>>>(ctx, 768, 768, Wo + (size_t)lyr * 589824, 768,
                                         bo + lyr * 768, tmp, 768, 32);
    k_ln<<<2048, 256, 0, stream>>>(tmp, xf, g1 + lyr * 768, be1 + lyr * 768, aof, aob);
    k_gemm_gelu<<<1536, 256, 0, stream>>>(aob, 768, 768, Wi + (size_t)lyr * 2359296, 3072,
                                          bi + lyr * 3072, hb, 3072, 32);
    k_gemm_bias<<<384, 256, 0, stream>>>(hb, 3072, 3072, W2 + (size_t)lyr * 2359296, 768,
                                         b2 + lyr * 768, tmp, 768, 32);
    float* ox = (lyr == 11) ? (float*)d_out : xf;
    k_ln<<<2048, 256, 0, stream>>>(tmp, aof, g2 + lyr * 768, be2 + lyr * 768, ox, xb);
  }
}

// Round 4
// 2315.940 us; speedup vs baseline: 1.1682x; 1.1682x over previous
//
#include <hip/hip_runtime.h>
#include <hip/hip_bf16.h>

// LayoutLMv3 encoder forward, bf16-MFMA implementation.
// L=12 D=768 H=12 DH=64 FF=3072 B=4 S=512.
// R3: weights pre-tiled to bf16 LDS-images; GEMM staging via global_load_lds
// with LDS double-buffer + A-reg prefetch (one barrier per K-tile).

typedef __attribute__((ext_vector_type(8))) short short8;
typedef __attribute__((ext_vector_type(4))) float f32x4;
typedef __attribute__((ext_vector_type(4))) unsigned int u32x4;
typedef __attribute__((ext_vector_type(4))) unsigned short us4;

#define DEVI static __device__ __forceinline__

DEVI unsigned short f2bf(float f) {          // RNE f32 -> bf16
  union { float f; unsigned u; } x; x.f = f;
  unsigned u = x.u;
  u += 0x7fffu + ((u >> 16) & 1u);
  return (unsigned short)(u >> 16);
}
DEVI float bf2f(unsigned short h) {
  union { unsigned u; float f; } x; x.u = ((unsigned)h) << 16;
  return x.f;
}
// bijective XCD-contiguous block swizzle (m204 form)
DEVI int xcd_swz(int bid, int nwg) {
  int q = nwg >> 3, r = nwg & 7;
  int x = bid & 7, o = bid >> 3;
  return (x < r ? x * (q + 1) : r * (q + 1) + (x - r) * q) + o;
}

DEVI void gload16(const void* g, void* l) {   // async global->LDS, 16B/lane
  __builtin_amdgcn_global_load_lds((const __attribute__((address_space(1))) void*)g,
                                   (__attribute__((address_space(3))) void*)l, 16, 0, 0);
}

// =====================================================================
// Weight pre-pass: f32 W[K][N] tile (64k x 64n) -> 8KB bf16 LDS image.
// Image row n (128B): chunk c (16B) holds k-chunk (c ^ (n&7)) -> the GEMM's
// ds_read_b128 at addr n*128 + ((kc^(n&7))<<4) is bank-conflict-free.
__global__ __launch_bounds__(256) void k_prep(
    const float* __restrict__ W, unsigned short* __restrict__ dst,
    int K, int N, int nkt, int nbn) {
  __shared__ float sw[4096];
  int t = blockIdx.x;
  const int kt = t % nkt; t /= nkt;
  const int bn = t % nbn; t /= nbn;
  const int layer = t;
  const float* src = W + (size_t)layer * K * N + (size_t)(kt * 64) * N + bn * 64;
  const int tid = threadIdx.x;
  const int k = tid >> 2, n0 = (tid & 3) * 16;
#pragma unroll
  for (int j = 0; j < 4; ++j)
    *(f32x4*)(sw + k * 64 + n0 + j * 4) = *(const f32x4*)(src + (size_t)k * N + n0 + j * 4);
  __syncthreads();
  unsigned short* img = dst + ((size_t)((size_t)layer * nbn + bn) * nkt + kt) * 4096;
  const int n_loc = tid >> 2;
#pragma unroll
  for (int ci = 0; ci < 2; ++ci) {
    const int c = (tid & 3) + ci * 4;
    const int kc = c ^ (n_loc & 7);
    short8 out;
#pragma unroll
    for (int j = 0; j < 8; ++j) out[j] = (short)f2bf(sw[(kc * 8 + j) * 64 + n_loc]);
    *(short8*)(img + n_loc * 64 + c * 8) = out;
  }
}

// =====================================================================
// GEMM core v2: C(64x64) = A(bf16 global) @ W(pre-tiled bf16 images).
// 4 waves; wave w owns rows [16w,16w+16). BK=64; LDS dbuf 2x8KB; one
// barrier per K-tile; weight staged via global_load_lds; A prefetched.
DEVI void gemm64t(const unsigned short* __restrict__ A, int lda,
                  const unsigned short* __restrict__ tiles, int nkt,
                  int m0, f32x4 acc[4], char* lds) {
  const int tid = threadIdx.x, l = tid & 63, w = tid >> 6;
  const unsigned short* Ar = A + (size_t)(m0 + 16 * w + (l & 15)) * lda + ((l >> 4) << 3);
  char* buf0 = lds;
  char* buf1 = lds + 8192;
#define STAGE_T(b, kt)                                                        \
  {                                                                           \
    const char* s_ = (const char*)(tiles + (size_t)(kt) * 4096);              \
    int b0_ = (w * 64) * 16;                                                  \
    gload16(s_ + b0_ + l * 16, (b) + b0_);                                    \
    int b1_ = (256 + w * 64) * 16;                                            \
    gload16(s_ + b1_ + l * 16, (b) + b1_);                                    \
  }
  STAGE_T(buf0, 0);
  short8 aC0 = *(const short8*)(Ar);
  short8 aC1 = *(const short8*)(Ar + 32);
  __syncthreads();
  for (int kt = 0; kt < nkt; ++kt) {
    char* cur = (kt & 1) ? buf1 : buf0;
    char* nxt = (kt & 1) ? buf0 : buf1;
    short8 aN0 = aC0, aN1 = aC1;
    if (kt + 1 < nkt) {
      STAGE_T(nxt, kt + 1);
      aN0 = *(const short8*)(Ar + (kt + 1) * 64);
      aN1 = *(const short8*)(Ar + (kt + 1) * 64 + 32);
    }
#pragma unroll
    for (int ks = 0; ks < 2; ++ks) {
      short8 a = ks ? aC1 : aC0;
#pragma unroll
      for (int fb = 0; fb < 4; ++fb) {
        int nn = (fb << 4) + (l & 15);
        int kc = (ks << 2) + (l >> 4);
        int addr = (nn << 7) + ((kc ^ (nn & 7)) << 4);
        short8 b = *(const short8*)(cur + addr);
        acc[fb] = __builtin_amdgcn_mfma_f32_16x16x32_bf16(a, b, acc[fb], 0, 0, 0);
      }
    }
    __syncthreads();
    aC0 = aN0; aC1 = aN1;
  }
#undef STAGE_T
}

// ---- fused QKV (new path): n-tiles 0..11 Q (scaled 1/8), 12..23 K, 24..35 V^T
__global__ __launch_bounds__(256) void k_qkv2(
    const unsigned short* __restrict__ xb,
    const unsigned short* __restrict__ wQt, const unsigned short* __restrict__ wKt,
    const unsigned short* __restrict__ wVt,
    const float* __restrict__ bq, const float* __restrict__ bk, const float* __restrict__ bv,
    unsigned short* __restrict__ q_out, unsigned short* __restrict__ k_out,
    unsigned short* __restrict__ vT_out) {
  __shared__ u32x4 lds4[1024];
  char* lds = (char*)lds4;
  const int wid = xcd_swz(blockIdx.x, gridDim.x);
  const int bm = wid % 32, bn = wid / 32;
  const int which = bn / 12, nb = bn % 12;
  const unsigned short* tiles =
      (which == 0 ? wQt : which == 1 ? wKt : wVt) + (size_t)nb * 12 * 4096;
  const float* bias = (which == 0 ? bq : which == 1 ? bk : bv) + nb * 64;
  f32x4 acc[4];
#pragma unroll
  for (int i = 0; i < 4; ++i) acc[i] = (f32x4){0.f, 0.f, 0.f, 0.f};
  gemm64t(xb, 768, tiles, 12, bm * 64, acc, lds);
  const int tid = threadIdx.x, l = tid & 63, w = tid >> 6;
  const int r0 = bm * 64 + 16 * w + ((l >> 4) << 2);
  const int batch = r0 >> 9, s0 = r0 & 511;
  const int bh = batch * 12 + nb;
  const float scale = (which == 0) ? 0.125f : 1.0f;
#pragma unroll
  for (int fb = 0; fb < 4; ++fb) {
    const int c = (fb << 4) + (l & 15);
    const float bv_ = bias[c];
    if (which == 2) {
      us4 pk;
#pragma unroll
      for (int j = 0; j < 4; ++j) pk[j] = f2bf(acc[fb][j] + bv_);
      *(us4*)(vT_out + ((size_t)bh * 64 + c) * 512 + s0) = pk;
    } else {
      unsigned short* dst = (which == 0 ? q_out : k_out);
#pragma unroll
      for (int j = 0; j < 4; ++j)
        dst[((size_t)bh * 512 + s0 + j) * 64 + c] = f2bf((acc[fb][j] + bv_) * scale);
    }
  }
}

// ---- GEMM + bias -> f32 (new path)
__global__ __launch_bounds__(256) void k_gemm_bias2(
    const unsigned short* __restrict__ A, int lda,
    const unsigned short* __restrict__ tilesL, int nkt,
    const float* __restrict__ bias, float* __restrict__ outf, int N, int nbm) {
  __shared__ u32x4 lds4[1024];
  char* lds = (char*)lds4;
  const int wid = xcd_swz(blockIdx.x, gridDim.x);
  const int bm = wid % nbm, bn = wid / nbm;
  f32x4 acc[4];
#pragma unroll
  for (int i = 0; i < 4; ++i) acc[i] = (f32x4){0.f, 0.f, 0.f, 0.f};
  gemm64t(A, lda, tilesL + (size_t)bn * nkt * 4096, nkt, bm * 64, acc, lds);
  const int tid = threadIdx.x, l = tid & 63, w = tid >> 6;
  const int r0 = bm * 64 + 16 * w + ((l >> 4) << 2);
  const int c0 = bn * 64;
#pragma unroll
  for (int fb = 0; fb < 4; ++fb) {
    const int c = c0 + (fb << 4) + (l & 15);
    const float bb = bias[c];
#pragma unroll
    for (int j = 0; j < 4; ++j)
      outf[(size_t)(r0 + j) * N + c] = acc[fb][j] + bb;
  }
}

// ---- GEMM + bias + exact GELU -> bf16 (new path)
__global__ __launch_bounds__(256) void k_gemm_gelu2(
    const unsigned short* __restrict__ A, int lda,
    const unsigned short* __restrict__ tilesL, int nkt,
    const float* __restrict__ bias, unsigned short* __restrict__ outb, int N, int nbm) {
  __shared__ u32x4 lds4[1024];
  char* lds = (char*)lds4;
  const int wid = xcd_swz(blockIdx.x, gridDim.x);
  const int bm = wid % nbm, bn = wid / nbm;
  f32x4 acc[4];
#pragma unroll
  for (int i = 0; i < 4; ++i) acc[i] = (f32x4){0.f, 0.f, 0.f, 0.f};
  gemm64t(A, lda, tilesL + (size_t)bn * nkt * 4096, nkt, bm * 64, acc, lds);
  const int tid = threadIdx.x, l = tid & 63, w = tid >> 6;
  const int r0 = bm * 64 + 16 * w + ((l >> 4) << 2);
  const int c0 = bn * 64;
#pragma unroll
  for (int fb = 0; fb < 4; ++fb) {
    const int c = c0 + (fb << 4) + (l & 15);
    const float bb = bias[c];
#pragma unroll
    for (int j = 0; j < 4; ++j) {
      float v = acc[fb][j] + bb;
      v = 0.5f * v * (1.0f + erff(v * 0.70710678118654752f));
      outb[(size_t)(r0 + j) * N + c] = f2bf(v);
    }
  }
}

// =====================================================================
// ==== legacy f32-weight GEMM path (fallback when ws too small) =======
DEVI void gemm64(const unsigned short* __restrict__ A, int lda,
                 const float* __restrict__ W, int ldw, int K,
                 int m0, f32x4 acc[4], char* lds) {
  const int tid = threadIdx.x;
  const int l = tid & 63, w = tid >> 6;
  const int n_st = tid & 63;
  const int kb = (tid >> 6) << 4;
  const unsigned short* Ar = A + (size_t)(m0 + 16 * w + (l & 15)) * lda + ((l >> 4) << 3);
  for (int kt = 0; kt < K; kt += 64) {
    float f[16];
#pragma unroll
    for (int j = 0; j < 16; ++j)
      f[j] = W[(size_t)(kt + kb + j) * ldw + n_st];
    __syncthreads();
#pragma unroll
    for (int c = 0; c < 2; ++c) {
      u32x4 p;
#pragma unroll
      for (int q2 = 0; q2 < 4; ++q2)
        p[q2] = (unsigned)f2bf(f[c * 8 + q2 * 2]) | ((unsigned)f2bf(f[c * 8 + q2 * 2 + 1]) << 16);
      int koff = (kb + c * 8) << 1;
      int addr = (n_st << 7) + (koff ^ ((n_st & 7) << 4));
      *(u32x4*)(lds + addr) = p;
    }
    __syncthreads();
#pragma unroll
    for (int ks = 0; ks < 2; ++ks) {
      short8 a = *(const short8*)(Ar + kt + ks * 32);
#pragma unroll
      for (int fb = 0; fb < 4; ++fb) {
        int nn = (fb << 4) + (l & 15);
        int koff = (ks * 32 + ((l >> 4) << 3)) << 1;
        int addr = (nn << 7) + (koff ^ ((nn & 7) << 4));
        short8 b = *(const short8*)(lds + addr);
        acc[fb] = __builtin_amdgcn_mfma_f32_16x16x32_bf16(a, b, acc[fb], 0, 0, 0);
      }
    }
  }
}

__global__ __launch_bounds__(256) void k_qkv(
    const unsigned short* __restrict__ xb,
    const float* __restrict__ Wq, const float* __restrict__ Wk, const float* __restrict__ Wv,
    const float* __restrict__ bq, const float* __restrict__ bk, const float* __restrict__ bv,
    unsigned short* __restrict__ q_out, unsigned short* __restrict__ k_out,
    unsigned short* __restrict__ vT_out, int layer) {
  __shared__ u32x4 lds4[512];
  char* lds = (char*)lds4;
  const int wid = xcd_swz(blockIdx.x, gridDim.x);
  const int bm = wid % 32, bn = wid / 32;
  const int which = bn / 12;
  const int nloc = (bn % 12) * 64;
  const float* W = (which == 0 ? Wq : which == 1 ? Wk : Wv) + (size_t)layer * 589824 + nloc;
  const float* bias = (which == 0 ? bq : which == 1 ? bk : bv) + layer * 768 + nloc;
  f32x4 acc[4];
#pragma unroll
  for (int i = 0; i < 4; ++i) acc[i] = (f32x4){0.f, 0.f, 0.f, 0.f};
  gemm64(xb, 768, W, 768, 768, bm * 64, acc, lds);
  const int tid = threadIdx.x, l = tid & 63, w = tid >> 6;
  const int h = nloc >> 6;
  const int r0 = bm * 64 + 16 * w + ((l >> 4) << 2);
  const int batch = r0 >> 9, s0 = r0 & 511;
  const int bh = batch * 12 + h;
  const float scale = (which == 0) ? 0.125f : 1.0f;
#pragma unroll
  for (int fb = 0; fb < 4; ++fb) {
    const int c = (fb << 4) + (l & 15);
    const float bv_ = bias[c];
    if (which == 2) {
      us4 pk;
#pragma unroll
      for (int j = 0; j < 4; ++j) pk[j] = f2bf(acc[fb][j] + bv_);
      *(us4*)(vT_out + ((size_t)bh * 64 + c) * 512 + s0) = pk;
    } else {
      unsigned short* dst = (which == 0 ? q_out : k_out);
#pragma unroll
      for (int j = 0; j < 4; ++j)
        dst[((size_t)bh * 512 + s0 + j) * 64 + c] = f2bf((acc[fb][j] + bv_) * scale);
    }
  }
}

__global__ __launch_bounds__(256) void k_gemm_bias(
    const unsigned short* __restrict__ A, int lda, int K,
    const float* __restrict__ W, int ldw,
    const float* __restrict__ bias, float* __restrict__ outf, int N, int nbm) {
  __shared__ u32x4 lds4[512];
  char* lds = (char*)lds4;
  const int wid = xcd_swz(blockIdx.x, gridDim.x);
  const int bm = wid % nbm, bn = wid / nbm;
  f32x4 acc[4];
#pragma unroll
  for (int i = 0; i < 4; ++i) acc[i] = (f32x4){0.f, 0.f, 0.f, 0.f};
  gemm64(A, lda, W + bn * 64, ldw, K, bm * 64, acc, lds);
  const int tid = threadIdx.x, l = tid & 63, w = tid >> 6;
  const int r0 = bm * 64 + 16 * w + ((l >> 4) << 2);
  const int c0 = bn * 64;
#pragma unroll
  for (int fb = 0; fb < 4; ++fb) {
    const int c = c0 + (fb << 4) + (l & 15);
    const float bb = bias[c];
#pragma unroll
    for (int j = 0; j < 4; ++j)
      outf[(size_t)(r0 + j) * N + c] = acc[fb][j] + bb;
  }
}

__global__ __launch_bounds__(256) void k_gemm_gelu(
    const unsigned short* __restrict__ A, int lda, int K,
    const float* __restrict__ W, int ldw,
    const float* __restrict__ bias, unsigned short* __restrict__ outb, int N, int nbm) {
  __shared__ u32x4 lds4[512];
  char* lds = (char*)lds4;
  const int wid = xcd_swz(blockIdx.x, gridDim.x);
  const int bm = wid % nbm, bn = wid / nbm;
  f32x4 acc[4];
#pragma unroll
  for (int i = 0; i < 4; ++i) acc[i] = (f32x4){0.f, 0.f, 0.f, 0.f};
  gemm64(A, lda, W + bn * 64, ldw, K, bm * 64, acc, lds);
  const int tid = threadIdx.x, l = tid & 63, w = tid >> 6;
  const int r0 = bm * 64 + 16 * w + ((l >> 4) << 2);
  const int c0 = bn * 64;
#pragma unroll
  for (int fb = 0; fb < 4; ++fb) {
    const int c = c0 + (fb << 4) + (l & 15);
    const float bb = bias[c];
#pragma unroll
    for (int j = 0; j < 4; ++j) {
      float v = acc[fb][j] + bb;
      v = 0.5f * v * (1.0f + erff(v * 0.70710678118654752f));
      outb[(size_t)(r0 + j) * N + c] = f2bf(v);
    }
  }
}

// =====================================================================
// ---- attention: scores + bias + softmax -> probs (bf16)
__global__ __launch_bounds__(256) void k_attn(
    const unsigned short* __restrict__ qb, const unsigned short* __restrict__ kb,
    const unsigned short* __restrict__ biasb, unsigned short* __restrict__ probs) {
  const int bh = blockIdx.y;
  const int q0 = blockIdx.x * 64;
  const int tid = threadIdx.x, l = tid & 63, w = tid >> 6;
  const unsigned short* Q = qb + ((size_t)bh * 512 + q0 + 16 * w + (l & 15)) * 64 + ((l >> 4) << 3);
  const unsigned short* Kp = kb + (size_t)bh * 32768 + (size_t)(l & 15) * 64 + ((l >> 4) << 3);
  f32x4 acc[32];
#pragma unroll
  for (int i = 0; i < 32; ++i) acc[i] = (f32x4){0.f, 0.f, 0.f, 0.f};
#pragma unroll
  for (int ks = 0; ks < 2; ++ks) {
    short8 a = *(const short8*)(Q + ks * 32);
#pragma unroll
    for (int f = 0; f < 32; ++f) {
      short8 b = *(const short8*)(Kp + (size_t)f * 1024 + ks * 32);
      acc[f] = __builtin_amdgcn_mfma_f32_16x16x32_bf16(a, b, acc[f], 0, 0, 0);
    }
  }
  const int r0 = q0 + 16 * w + ((l >> 4) << 2);
  const unsigned short* Brow = biasb + ((size_t)bh * 512 + r0) * 512 + (l & 15);
  unsigned short* Prow = probs + ((size_t)bh * 512 + r0) * 512 + (l & 15);
#pragma unroll
  for (int j = 0; j < 4; ++j) {
    float m = -3.0e38f;
#pragma unroll
    for (int f = 0; f < 32; ++f) {
      float v = acc[f][j] + bf2f(Brow[(size_t)j * 512 + (f << 4)]);
      acc[f][j] = v;
      m = fmaxf(m, v);
    }
#pragma unroll
    for (int off = 1; off < 16; off <<= 1) m = fmaxf(m, __shfl_xor(m, off));
    float s = 0.f;
#pragma unroll
    for (int f = 0; f < 32; ++f) {
      float e = __expf(acc[f][j] - m);
      acc[f][j] = e;
      s += e;
    }
#pragma unroll
    for (int off = 1; off < 16; off <<= 1) s += __shfl_xor(s, off);
    const float inv = 1.0f / s;
#pragma unroll
    for (int f = 0; f < 32; ++f)
      Prow[(size_t)j * 512 + (f << 4)] = f2bf(acc[f][j] * inv);
  }
}

// ---- PV: ctx = probs @ V (V from transposed vT)
__global__ __launch_bounds__(256) void k_pv(
    const unsigned short* __restrict__ probs, const unsigned short* __restrict__ vT,
    unsigned short* __restrict__ ctx) {
  const int bh = blockIdx.y;
  const int q0 = blockIdx.x * 64;
  const int tid = threadIdx.x, l = tid & 63, w = tid >> 6;
  const unsigned short* Ar = probs + ((size_t)bh * 512 + q0 + 16 * w + (l & 15)) * 512 + ((l >> 4) << 3);
  const unsigned short* Vb = vT + (size_t)bh * 32768 + (size_t)(l & 15) * 512 + ((l >> 4) << 3);
  f32x4 acc[4];
#pragma unroll
  for (int i = 0; i < 4; ++i) acc[i] = (f32x4){0.f, 0.f, 0.f, 0.f};
#pragma unroll 4
  for (int kt = 0; kt < 512; kt += 32) {
    short8 a = *(const short8*)(Ar + kt);
#pragma unroll
    for (int f = 0; f < 4; ++f) {
      short8 b = *(const short8*)(Vb + (size_t)f * 8192 + kt);
      acc[f] = __builtin_amdgcn_mfma_f32_16x16x32_bf16(a, b, acc[f], 0, 0, 0);
    }
  }
  const int batch = bh / 12, h = bh % 12;
  const int r0 = q0 + 16 * w + ((l >> 4) << 2);
#pragma unroll
  for (int fb = 0; fb < 4; ++fb) {
    const int c = (fb << 4) + (l & 15);
#pragma unroll
    for (int j = 0; j < 4; ++j)
      ctx[((size_t)(batch * 512 + r0 + j)) * 768 + h * 64 + c] = f2bf(acc[fb][j]);
  }
}

// ---- residual + LayerNorm, writes f32 + bf16
__global__ __launch_bounds__(256) void k_ln(
    const float* __restrict__ x, const float* __restrict__ res,
    const float* __restrict__ g, const float* __restrict__ bb,
    float* __restrict__ outf, unsigned short* __restrict__ outb) {
  const int row = blockIdx.x, tid = threadIdx.x;
  const float* X = x + (size_t)row * 768;
  const float* R = res + (size_t)row * 768;
  float v[3];
  float s = 0.f;
#pragma unroll
  for (int i = 0; i < 3; ++i) { v[i] = X[tid + (i << 8)] + R[tid + (i << 8)]; s += v[i]; }
  __shared__ float red[4];
#pragma unroll
  for (int off = 32; off; off >>= 1) s += __shfl_xor(s, off);
  if ((tid & 63) == 0) red[tid >> 6] = s;
  __syncthreads();
  const float mu = (red[0] + red[1] + red[2] + red[3]) * (1.f / 768.f);
  float s2 = 0.f;
#pragma unroll
  for (int i = 0; i < 3; ++i) { float d = v[i] - mu; s2 += d * d; }
  __syncthreads();
#pragma unroll
  for (int off = 32; off; off >>= 1) s2 += __shfl_xor(s2, off);
  if ((tid & 63) == 0) red[tid >> 6] = s2;
  __syncthreads();
  const float rstd = rsqrtf((red[0] + red[1] + red[2] + red[3]) * (1.f / 768.f) + 1e-5f);
#pragma unroll
  for (int i = 0; i < 3; ++i) {
    const int c = tid + (i << 8);
    const float o = (v[i] - mu) * rstd * g[c] + bb[c];
    outf[(size_t)row * 768 + c] = o;
    outb[(size_t)row * 768 + c] = f2bf(o);
  }
}

__global__ __launch_bounds__(256) void k_init(const float* __restrict__ h,
                                              float* __restrict__ xf,
                                              unsigned short* __restrict__ xb, int n) {
  int i = blockIdx.x * 256 + threadIdx.x;
  if (i < n) { float v = h[i]; xf[i] = v; xb[i] = f2bf(v); }
}

// ---- relative-position bucket (exact int semantics)
DEVI int rbucket(int rp, int nb, int mex) {
  int ret = rp > 0 ? nb : 0;
  int n = rp < 0 ? -rp : rp;
  if (n < mex) return ret + n;
  float v = logf((float)n / (float)mex) * 0.36067376022224085f * (float)(nb - mex);
  int vi = mex + (int)v;
  vi = vi < (nb - 1) ? vi : (nb - 1);
  return ret + vi;
}

__global__ __launch_bounds__(256) void k_bias(
    const int* __restrict__ pos, const int* __restrict__ bbox,
    const float* __restrict__ mask,
    const float* __restrict__ rel_w, const float* __restrict__ relx_w,
    const float* __restrict__ rely_w, unsigned short* __restrict__ biasb) {
  __shared__ float tw[1920];
  for (int i = threadIdx.x; i < 1920; i += 256)
    tw[i] = i < 384 ? rel_w[i] : (i < 1152 ? relx_w[i - 384] : rely_w[i - 1152]);
  __syncthreads();
  const int blk = blockIdx.x;
  const int b = blk >> 9, qi = blk & 511;
  const int pi = pos[(b << 9) + qi];
  const int pxi = bbox[(((b << 9) + qi) << 2) + 0];
  const int pyi = bbox[(((b << 9) + qi) << 2) + 3];
  for (int j = threadIdx.x; j < 512; j += 256) {
    const int idx = (b << 9) + j;
    const int b1 = rbucket(pos[idx] - pi, 16, 8);
    const int bx = rbucket(bbox[(idx << 2) + 0] - pxi, 32, 16);
    const int by = rbucket(bbox[(idx << 2) + 3] - pyi, 32, 16);
    const float mk = mask[idx];
    const float* r1 = tw + b1 * 12;
    const float* r2 = tw + 384 + bx * 12;
    const float* r3 = tw + 1152 + by * 12;
#pragma unroll
    for (int h = 0; h < 12; ++h) {
      float v = (r1[h] + r2[h] + r3[h]) * 0.125f + mk;
      biasb[(((size_t)(b * 12 + h) * 512) + qi) * 512 + j] = f2bf(v);
    }
  }
}

extern "C" void kernel_launch(void* const* d_in, const int* in_sizes, int n_in,
                              void* d_out, int out_size, void* d_ws, size_t ws_size,
                              hipStream_t stream) {
  const float* hid  = (const float*)d_in[0];
  const float* mask = (const float*)d_in[1];
  const int*   pos  = (const int*)d_in[2];
  const int*   bbx  = (const int*)d_in[3];
  const float* Wq = (const float*)d_in[4];  const float* bq = (const float*)d_in[5];
  const float* Wk = (const float*)d_in[6];  const float* bk = (const float*)d_in[7];
  const float* Wv = (const float*)d_in[8];  const float* bv = (const float*)d_in[9];
  const float* Wo = (const float*)d_in[10]; const float* bo = (const float*)d_in[11];
  const float* g1 = (const float*)d_in[12]; const float* be1 = (const float*)d_in[13];
  const float* Wi = (const float*)d_in[14]; const float* bi = (const float*)d_in[15];
  const float* W2 = (const float*)d_in[16]; const float* b2 = (const float*)d_in[17];
  const float* g2 = (const float*)d_in[18]; const float* be2 = (const float*)d_in[19];
  const float* relw  = (const float*)d_in[20];
  const float* relxw = (const float*)d_in[21];
  const float* relyw = (const float*)d_in[22];

  char* ws = (char*)d_ws;
  size_t off = 0;
  auto alloc = [&](size_t b) -> char* {
    char* p = ws + off; off += (b + 255) & ~(size_t)255; return p;
  };
  unsigned short* biasb = (unsigned short*)alloc(25165824); // [48][512][512] bf16
  unsigned short* probs = (unsigned short*)alloc(25165824);
  float* xf  = (float*)alloc(6291456);
  float* tmp = (float*)alloc(6291456);
  float* aof = (float*)alloc(6291456);
  unsigned short* xb  = (unsigned short*)alloc(3145728);
  unsigned short* qb  = (unsigned short*)alloc(3145728);
  unsigned short* kb  = (unsigned short*)alloc(3145728);
  unsigned short* vT  = (unsigned short*)alloc(3145728);
  unsigned short* ctx = (unsigned short*)alloc(3145728);
  unsigned short* aob = (unsigned short*)alloc(3145728);
  unsigned short* hb  = (unsigned short*)alloc(12582912);  // [2048][3072] bf16
  const size_t act_need = off;

  // weight images (bf16, pre-tiled): per 64x64 tile = 4096 shorts
  const size_t szP = (size_t)12 * 12 * 12 * 4096 * 2;   // 768x768 proj, 12 layers
  const size_t szF = (size_t)12 * 48 * 12 * 4096 * 2;   // 768x3072 / 3072x768
  unsigned short* imgQ = (unsigned short*)alloc(szP);
  unsigned short* imgK = (unsigned short*)alloc(szP);
  unsigned short* imgV = (unsigned short*)alloc(szP);
  unsigned short* imgO = (unsigned short*)alloc(szP);
  unsigned short* imgI = (unsigned short*)alloc(szF);
  unsigned short* img2 = (unsigned short*)alloc(szF);
  const bool big = (off <= ws_size);
  (void)act_need;

  k_bias<<<2048, 256, 0, stream>>>(pos, bbx, mask, relw, relxw, relyw, biasb);
  k_init<<<6144, 256, 0, stream>>>(hid, xf, xb, 2048 * 768);

  if (big) {
    k_prep<<<1728, 256, 0, stream>>>(Wq, imgQ, 768, 768, 12, 12);
    k_prep<<<1728, 256, 0, stream>>>(Wk, imgK, 768, 768, 12, 12);
    k_prep<<<1728, 256, 0, stream>>>(Wv, imgV, 768, 768, 12, 12);
    k_prep<<<1728, 256, 0, stream>>>(Wo, imgO, 768, 768, 12, 12);
    k_prep<<<6912, 256, 0, stream>>>(Wi, imgI, 768, 3072, 12, 48);
    k_prep<<<6912, 256, 0, stream>>>(W2, img2, 3072, 768, 48, 12);
  }

  for (int lyr = 0; lyr < 12; ++lyr) {
    if (big) {
      k_qkv2<<<1152, 256, 0, stream>>>(xb,
          imgQ + (size_t)lyr * 144 * 4096, imgK + (size_t)lyr * 144 * 4096,
          imgV + (size_t)lyr * 144 * 4096,
          bq + lyr * 768, bk + lyr * 768, bv + lyr * 768, qb, kb, vT);
    } else {
      k_qkv<<<1152, 256, 0, stream>>>(xb, Wq, Wk, Wv, bq, bk, bv, qb, kb, vT, lyr);
    }
    k_attn<<<dim3(8, 48), 256, 0, stream>>>(qb, kb, biasb, probs);
    k_pv<<<dim3(8, 48), 256, 0, stream>>>(probs, vT, ctx);
    if (big) {
      k_gemm_bias2<<<384, 256, 0, stream>>>(ctx, 768,
          imgO + (size_t)lyr * 144 * 4096, 12, bo + lyr * 768, tmp, 768, 32);
    } else {
      k_gemm_bias<<<384, 256, 0, stream>>>(ctx, 768, 768, Wo + (size_t)lyr * 589824, 768,
                                           bo + lyr * 768, tmp, 768, 32);
    }
    k_ln<<<2048, 256, 0, stream>>>(tmp, xf, g1 + lyr * 768, be1 + lyr * 768, aof, aob);
    if (big) {
      k_gemm_gelu2<<<1536, 256, 0, stream>>>(aob, 768,
          imgI + (size_t)lyr * 576 * 4096, 12, bi + lyr * 3072, hb, 3072, 32);
      k_gemm_bias2<<<384, 256, 0, stream>>>(hb, 3072,
          img2 + (size_t)lyr * 576 * 4096, 48, b2 + lyr * 768, tmp, 768, 32);
    } else {
      k_gemm_gelu<<<1536, 256, 0, stream>>>(aob, 768, 768, Wi + (size_t)lyr * 2359296, 3072,
                                            bi + lyr * 3072, hb, 3072, 32);
      k_gemm_bias<<<384, 256, 0, stream>>>(hb, 3072, 3072, W2 + (size_t)lyr * 2359296, 768,
                                           b2 + lyr * 768, tmp, 768, 32);
    }
    float* ox = (lyr == 11) ? (float*)d_out : xf;
    k_ln<<<2048, 256, 0, stream>>>(tmp, aof, g2 + lyr * 768, be2 + lyr * 768, ox, xb);
  }
}